// Round 10
// baseline (725.149 us; speedup 1.0000x reference)
//
#include <hip/hip_runtime.h>
#include <math.h>

namespace {
constexpr int kB = 4096;
constexpr int kD = 9216;   // 64*12*12
constexpr int kE = 8;
constexpr int kH = 128;
constexpr int kO = 10;
constexpr int PSTR = 32;   // shorts per h1 pixel (64 B stride)
constexpr int KSPLIT = 8;  // expert GEMM k-split: 9216/8 = 1152

typedef __attribute__((ext_vector_type(8))) short short8;   // 8 bf16
typedef __attribute__((ext_vector_type(4))) float f32x4;    // MFMA acc

__device__ inline unsigned f2bf(float f) {  // fp32 -> bf16 bits, RNE
  unsigned u = __float_as_uint(f);
  return (u + 0x7fffu + ((u >> 16) & 1u)) >> 16;
}
__device__ inline float bf2f(unsigned b) { return __uint_as_float(b << 16); }

// w1 -> MFMA B-frag order, bf16 hi/lo. Layout:
// [e][k>>5][nt][lane][j], lane = ((k>>3)&3)<<4 | (n&15), j = k&7.
// Block 0 additionally packs c2w B-frags and zeroes counts.
__global__ __launch_bounds__(256) void prep_w1(
    const float* __restrict__ w1, ushort* __restrict__ w1ph,
    ushort* __restrict__ w1pl, const float* __restrict__ c2w,
    ushort* __restrict__ Bph, ushort* __restrict__ Bpl,
    int* __restrict__ counts) {
  if (blockIdx.x == 0) {
    if (threadIdx.x < kE) counts[threadIdx.x] = 0;
    for (int i = threadIdx.x; i < 9 * 4 * 64 * 8; i += 256) {
      int j = i & 7, lane = (i >> 3) & 63, nt = (i >> 9) & 3, tap = i >> 11;
      int n = nt * 16 + (lane & 15);
      int c1 = (lane >> 4) * 8 + j;
      float v = c2w[(n * 32 + c1) * 9 + tap];
      unsigned hb = f2bf(v);
      Bph[i] = (ushort)hb;
      Bpl[i] = (ushort)f2bf(v - bf2f(hb));
    }
  }
  int t = blockIdx.x * 256 + threadIdx.x;
  int n = t & 127;
  int rem = t >> 7;
  int k8 = rem % 1152;
  int e = rem / 1152;
  const float* src = w1 + ((size_t)e * kD + (size_t)k8 * 8) * kH + n;
  short8 sh, sl;
#pragma unroll
  for (int j = 0; j < 8; ++j) {
    float v = src[(size_t)j * kH];
    unsigned hb = f2bf(v);
    sh[j] = (short)hb;
    sl[j] = (short)f2bf(v - bf2f(hb));
  }
  size_t base =
      ((((size_t)e * 288 + (k8 >> 2)) * 8 + (n >> 4)) * 64 +
       (((k8 & 3) << 4) | (n & 15))) * 8;
  *(short8*)(w1ph + base) = sh;
  *(short8*)(w1pl + base) = sl;
}

// One 256-thread block per sample. R9 body verbatim; launch bounds now plain
// (256): the ",2" min-waves arg appears to emit amdgpu-waves-per-eu metadata
// that CAPS occupancy at 2 blocks/CU (R5/R6: occupancy pinned at 22% across
// 51KB->31KB LDS and 128->100 VGPR — no resource explains a 2-block cap).
// LDS allows 3 blocks (153.6/160 KB), VGPR 128 allows 4 waves/SIMD.
// NUMERICS FROZEN: FMA/pack/MFMA sequence per output identical to R2/R4/R5/R9.
__global__ __launch_bounds__(256) void conv_kernel(
    const float* __restrict__ x, const float* __restrict__ c1w,
    const float* __restrict__ c1b, const float* __restrict__ b2g,
    const ushort* __restrict__ Bph, const ushort* __restrict__ Bpl,
    float* __restrict__ h) {
  __shared__ float xs[784];
  __shared__ float w1s[288];
  __shared__ float b1s[32];
  __shared__ ushort h1h[364 * PSTR];  // 23.3 KB
  __shared__ ushort h1l[364 * PSTR];
  const int b = blockIdx.x, tid = threadIdx.x;
  const int lane = tid & 63, wave = tid >> 6;
  const int np = wave & 1;   // channel pair-tile (32 chans)
  const int mh = wave >> 1;  // half of the 18 mt tiles

  short8 Bh[9][2], Bl[9][2];
#pragma unroll
  for (int tap = 0; tap < 9; ++tap)
#pragma unroll
    for (int t = 0; t < 2; ++t) {
      int fi = ((tap * 4 + np * 2 + t) * 64 + lane) * 8;
      Bh[tap][t] = *(const short8*)(Bph + fi);
      Bl[tap][t] = *(const short8*)(Bpl + fi);
    }
  float b2v0 = b2g[np * 32 + (lane & 15)];
  float b2v1 = b2g[np * 32 + 16 + (lane & 15)];

  const float* xb = x + (size_t)b * 784;
  for (int i = tid; i < 784; i += 256) xs[i] = xb[i];
  for (int i = tid; i < 288; i += 256) w1s[i] = c1w[i];
  if (tid < 32) b1s[tid] = c1b[tid];
  __syncthreads();

  float* hb = h + (size_t)b * kD;
  for (int pass = 0; pass < 2; ++pass) {
    for (int i = tid; i < 364 * 16; i += 256) {
      int p = i >> 4, cp = (i & 15) * 2;
      int r = p / 26, col = p - r * 26;
      const float* xr = xs + (pass * 12 + r) * 28 + col;
      const float* w0 = w1s + cp * 9;
      float v0 = b1s[cp], v1 = b1s[cp + 1];
#pragma unroll
      for (int ky = 0; ky < 3; ++ky)
#pragma unroll
        for (int kx = 0; kx < 3; ++kx) {
          float xv = xr[ky * 28 + kx];
          v0 += xv * w0[ky * 3 + kx];
          v1 += xv * w0[9 + ky * 3 + kx];
        }
      v0 = fmaxf(v0, 0.f);
      v1 = fmaxf(v1, 0.f);
      unsigned h0 = f2bf(v0), h1b = f2bf(v1);
      unsigned l0 = f2bf(v0 - bf2f(h0)), l1 = f2bf(v1 - bf2f(h1b));
      *(unsigned*)&h1h[p * PSTR + cp] = h0 | (h1b << 16);
      *(unsigned*)&h1l[p * PSTR + cp] = l0 | (l1 << 16);
    }
    __syncthreads();
    const int m = lane & 15, kg = lane >> 4;
    for (int mt = mh * 9; mt < mh * 9 + 9; ++mt) {
      int cell = mt * 4 + (m >> 2), sub = m & 3;
      int cy = cell / 12, cx = cell - cy * 12;
      int yy = 2 * cy + (sub >> 1), xx = 2 * cx + (sub & 1);
      const ushort* ah = h1h + (yy * 26 + xx) * PSTR + kg * 8;
      const ushort* al = h1l + (yy * 26 + xx) * PSTR + kg * 8;
      f32x4 acc0 = {0.f, 0.f, 0.f, 0.f};
      f32x4 acc1 = {0.f, 0.f, 0.f, 0.f};
#pragma unroll
      for (int ky = 0; ky < 3; ++ky)
#pragma unroll
        for (int kx = 0; kx < 3; ++kx) {
          const int tap = ky * 3 + kx;
          short8 Ah = *(const short8*)(ah + (ky * 26 + kx) * PSTR);  // b128
          short8 Al = *(const short8*)(al + (ky * 26 + kx) * PSTR);
          acc0 = __builtin_amdgcn_mfma_f32_16x16x32_bf16(Al, Bh[tap][0], acc0, 0, 0, 0);
          acc0 = __builtin_amdgcn_mfma_f32_16x16x32_bf16(Ah, Bl[tap][0], acc0, 0, 0, 0);
          acc0 = __builtin_amdgcn_mfma_f32_16x16x32_bf16(Ah, Bh[tap][0], acc0, 0, 0, 0);
          acc1 = __builtin_amdgcn_mfma_f32_16x16x32_bf16(Al, Bh[tap][1], acc1, 0, 0, 0);
          acc1 = __builtin_amdgcn_mfma_f32_16x16x32_bf16(Ah, Bl[tap][1], acc1, 0, 0, 0);
          acc1 = __builtin_amdgcn_mfma_f32_16x16x32_bf16(Ah, Bh[tap][1], acc1, 0, 0, 0);
        }
      int cellg = mt * 4 + kg;
      int gy = cellg / 12, gx = cellg - gy * 12;
      int orow = (pass * 6 + gy) * 12 + gx;
      float p0 = fmaxf(fmaxf(acc0[0], acc0[1]), fmaxf(acc0[2], acc0[3]));
      float p1 = fmaxf(fmaxf(acc1[0], acc1[1]), fmaxf(acc1[2], acc1[3]));
      hb[(np * 32 + m) * 144 + orow] = fmaxf(p0 + b2v0, 0.f);
      hb[(np * 32 + 16 + m) * 144 + orow] = fmaxf(p1 + b2v1, 0.f);
    }
    __syncthreads();
  }
}

// 4 tokens per 256-thread block; per-wave numerics frozen (R5 verbatim).
__global__ __launch_bounds__(256) void gate_kernel(
    const float* __restrict__ h, const float* __restrict__ gw,
    int* __restrict__ idx, float* __restrict__ scale,
    int* __restrict__ counts) {
  const int b = blockIdx.x * 4 + (threadIdx.x >> 6);
  const int lane = threadIdx.x & 63;
  const float* hb = h + (size_t)b * kD;
  float acc[kE] = {0, 0, 0, 0, 0, 0, 0, 0};
  for (int i = lane; i < kD; i += 64) {
    float hv = hb[i];
    const float* g = gw + (size_t)i * kE;
#pragma unroll
    for (int e = 0; e < kE; ++e) acc[e] += hv * g[e];
  }
#pragma unroll
  for (int off = 32; off > 0; off >>= 1) {
#pragma unroll
    for (int e = 0; e < kE; ++e) acc[e] += __shfl_down(acc[e], off, 64);
  }
  if (lane == 0) {
    float m = acc[0];
    int bi = 0;
#pragma unroll
    for (int e = 1; e < kE; ++e)
      if (acc[e] > m) { m = acc[e]; bi = e; }
    float s = 0.f;
#pragma unroll
    for (int e = 0; e < kE; ++e) s += expf(acc[e] - m);
    idx[b] = bi;
    scale[b] = 1.0f / s;
    atomicAdd(&counts[bi], 1);
  }
}

// Single block: exclusive scan of counts + bucket scatter via LDS cursors.
__global__ __launch_bounds__(256) void scan_scatter(
    const int* __restrict__ counts, const int* __restrict__ idx,
    int* __restrict__ offsets, int* __restrict__ perm) {
  __shared__ int soff[kE + 1];
  __shared__ int cur[kE];
  if (threadIdx.x == 0) {
    int o = 0;
    for (int e = 0; e < kE; ++e) {
      soff[e] = o;
      cur[e] = o;
      o += counts[e];
    }
    soff[kE] = o;
  }
  __syncthreads();
  for (int b = threadIdx.x; b < kB; b += 256) {
    int e = idx[b];
    int pos = atomicAdd(&cur[e], 1);
    perm[pos] = b;
  }
  if (threadIdx.x <= kE) offsets[threadIdx.x] = soff[threadIdx.x];
}

// MFMA expert GEMM. Grid (e=8, ks=8, tile=16). B staged through LDS once per
// block per bk (R9 win). Numerics frozen vs R4-R9.
__global__ __launch_bounds__(256) void expert_gemm(
    const float* __restrict__ h, const ushort* __restrict__ w1ph,
    const ushort* __restrict__ w1pl, const int* __restrict__ perm,
    const int* __restrict__ offsets, float* __restrict__ preact) {
  const int e = blockIdx.x, ks = blockIdx.y;
  const int start = offsets[e] + blockIdx.z * 64;
  const int end = offsets[e + 1];
  if (start >= end) return;
  const int M = min(64, end - start);
  __shared__ ushort Afh[4096];  // A frags [kstep][g][lane][8], 8 KB
  __shared__ ushort Afl[4096];
  __shared__ ushort Bsh[8192];  // B frags [kstep][nt][lane][8], 16 KB
  __shared__ ushort Bsl[8192];
  __shared__ int rows[64];
  const int tid = threadIdx.x;
  if (tid < 64) rows[tid] = perm[start + min(tid, M - 1)];
  __syncthreads();
  const int wave = tid >> 6, lane = tid & 63;
  const int m15 = lane & 15, kg4 = lane >> 4;
  const int srow = tid >> 2, spart = tid & 3;
  const int kbase = ks * (kD / KSPLIT);
  const float* hp0 = h + (size_t)rows[srow] * kD + kbase + spart * 16;
  const int skstep = spart >> 1, skg = (spart & 1) * 2;
  const int sg = srow >> 4, sm = srow & 15;
  ushort* wh0 = &Afh[((skstep * 4 + sg) * 64 + skg * 16 + sm) * 8];
  ushort* wl0 = &Afl[((skstep * 4 + sg) * 64 + skg * 16 + sm) * 8];
  f32x4 acc[8];
#pragma unroll
  for (int j = 0; j < 8; ++j) acc[j] = {0.f, 0.f, 0.f, 0.f};

  for (int bk = 0; bk < kD / KSPLIT; bk += 64) {
    // ---- stage A ----
#pragma unroll
    for (int c = 0; c < 2; ++c) {
      float4 v0 = *(const float4*)(hp0 + bk + c * 8);
      float4 v1 = *(const float4*)(hp0 + bk + c * 8 + 4);
      short8 ph, pl;
      float f[8] = {v0.x, v0.y, v0.z, v0.w, v1.x, v1.y, v1.z, v1.w};
#pragma unroll
      for (int j = 0; j < 8; ++j) {
        unsigned hb = f2bf(f[j]);
        ph[j] = (short)hb;
        pl[j] = (short)f2bf(f[j] - bf2f(hb));
      }
      *(short8*)(wh0 + c * 128) = ph;
      *(short8*)(wl0 + c * 128) = pl;
    }
    // ---- stage B: 2 kg32 blocks x 4096 shorts, contiguous in w1p ----
    {
      const size_t bbase =
          ((size_t)e * 288 + ((kbase + bk) >> 5)) * 4096;
#pragma unroll
      for (int q = 0; q < 4; ++q) {
        int c = tid + q * 256;  // b128 chunk id, 1024 total
        *(short8*)&Bsh[c * 8] = *(const short8*)(w1ph + bbase + (size_t)c * 8);
        *(short8*)&Bsl[c * 8] = *(const short8*)(w1pl + bbase + (size_t)c * 8);
      }
    }
    __syncthreads();
#pragma unroll
    for (int kstep = 0; kstep < 2; ++kstep) {
      const ushort* af = &Afh[((kstep * 4 + wave) * 64 + lane) * 8];
      short8 ah = *(const short8*)af;
      short8 al = *(const short8*)(af + (Afl - Afh));
      const ushort* bph = &Bsh[kstep * 4096 + lane * 8];
      const ushort* bpl = &Bsl[kstep * 4096 + lane * 8];
#pragma unroll
      for (int nt = 0; nt < 8; ++nt) {
        short8 bh = *(const short8*)(bph + nt * 512);
        short8 bl = *(const short8*)(bpl + nt * 512);
        acc[nt] = __builtin_amdgcn_mfma_f32_16x16x32_bf16(al, bh, acc[nt], 0, 0, 0);
        acc[nt] = __builtin_amdgcn_mfma_f32_16x16x32_bf16(ah, bl, acc[nt], 0, 0, 0);
        acc[nt] = __builtin_amdgcn_mfma_f32_16x16x32_bf16(ah, bh, acc[nt], 0, 0, 0);
      }
    }
    __syncthreads();
  }
  float* pb = preact + (size_t)ks * kB * kH;
#pragma unroll
  for (int r = 0; r < 4; ++r) {
    int row = wave * 16 + kg4 * 4 + r;
    if (row < M) {
      float* pr = pb + (size_t)rows[row] * kH + m15;
#pragma unroll
      for (int nt = 0; nt < 8; ++nt) pr[nt * 16] = acc[nt][r];
    }
  }
}

// Per-token tail: sum k-split slices, bias+relu, w2 matmul, scale, log_softmax.
__global__ __launch_bounds__(64) void expert_tail(
    const float* __restrict__ preact, const float* __restrict__ b1,
    const float* __restrict__ w2, const float* __restrict__ b2,
    const int* __restrict__ idx, const float* __restrict__ scale,
    float* __restrict__ out) {
  const int b = blockIdx.x;
  const int lane = threadIdx.x;
  const int e = idx[b];
  float pa = 0.f, pc = 0.f;
#pragma unroll
  for (int ks = 0; ks < KSPLIT; ++ks) {
    const float* ps = preact + ((size_t)ks * kB + b) * kH;
    pa += ps[lane];
    pc += ps[64 + lane];
  }
  float hea = fmaxf(pa + b1[e * kH + lane], 0.f);
  float heb = fmaxf(pc + b1[e * kH + 64 + lane], 0.f);
  const float* w2a = w2 + ((size_t)e * kH + lane) * kO;
  const float* w2b = w2a + 64 * kO;
  float part[kO];
#pragma unroll
  for (int o = 0; o < kO; ++o) part[o] = hea * w2a[o] + heb * w2b[o];
#pragma unroll
  for (int off = 32; off > 0; off >>= 1)
#pragma unroll
    for (int o = 0; o < kO; ++o) part[o] += __shfl_down(part[o], off, 64);
  if (lane == 0) {
    const float sc = scale[b];
    float v[kO], m = -1e30f;
#pragma unroll
    for (int o = 0; o < kO; ++o) {
      v[o] = (part[o] + b2[e * kO + o]) * sc;
      m = fmaxf(m, v[o]);
    }
    float s = 0.f;
#pragma unroll
    for (int o = 0; o < kO; ++o) s += expf(v[o] - m);
    const float lse = m + logf(s);
#pragma unroll
    for (int o = 0; o < kO; ++o) out[(size_t)b * kO + o] = v[o] - lse;
  }
}

}  // namespace

extern "C" void kernel_launch(void* const* d_in, const int* in_sizes, int n_in,
                              void* d_out, int out_size, void* d_ws,
                              size_t ws_size, hipStream_t stream) {
  (void)in_sizes; (void)n_in; (void)out_size; (void)ws_size;
  const float* x   = (const float*)d_in[0];
  const float* c1w = (const float*)d_in[1];
  const float* c1b = (const float*)d_in[2];
  const float* c2w = (const float*)d_in[3];
  const float* c2b = (const float*)d_in[4];
  const float* gw  = (const float*)d_in[5];
  const float* w1  = (const float*)d_in[6];
  const float* b1  = (const float*)d_in[7];
  const float* w2  = (const float*)d_in[8];
  const float* b2  = (const float*)d_in[9];
  float* out = (float*)d_out;

  char* ws = (char*)d_ws;
  float* h = (float*)ws;
  size_t off = (size_t)kB * kD * sizeof(float);                     // 151.0 MB
  ushort* w1ph = (ushort*)(ws + off); off += (size_t)kE * kD * kH * 2;  // 18.9 MB
  ushort* w1pl = (ushort*)(ws + off); off += (size_t)kE * kD * kH * 2;  // 18.9 MB
  float* preact = (float*)(ws + off); off += (size_t)KSPLIT * kB * kH * 4;  // 16.8 MB
  ushort* Bph = (ushort*)(ws + off);  off += 9 * 4 * 64 * 8 * 2;
  ushort* Bpl = (ushort*)(ws + off);  off += 9 * 4 * 64 * 8 * 2;
  int* idx = (int*)(ws + off);        off += (size_t)kB * 4;
  float* scale = (float*)(ws + off);  off += (size_t)kB * 4;
  int* perm = (int*)(ws + off);       off += (size_t)kB * 4;
  int* counts = (int*)(ws + off);     off += 64;
  int* offsets = (int*)(ws + off);    off += 64;

  prep_w1<<<4608, 256, 0, stream>>>(w1, w1ph, w1pl, c2w, Bph, Bpl, counts);
  conv_kernel<<<kB, 256, 0, stream>>>(x, c1w, c1b, c2b, Bph, Bpl, h);
  gate_kernel<<<kB / 4, 256, 0, stream>>>(h, gw, idx, scale, counts);
  scan_scatter<<<1, 256, 0, stream>>>(counts, idx, offsets, perm);
  dim3 eg(kE, KSPLIT, 16);
  expert_gemm<<<eg, 256, 0, stream>>>(h, w1ph, w1pl, perm, offsets, preact);
  expert_tail<<<kB, 64, 0, stream>>>(preact, b1, w2, b2, idx, scale, out);
}

// Round 11
// 544.824 us; speedup vs baseline: 1.3310x; 1.3310x over previous
//
#include <hip/hip_runtime.h>
#include <math.h>

namespace {
constexpr int kB = 4096;
constexpr int kD = 9216;   // 64*12*12
constexpr int kE = 8;
constexpr int kH = 128;
constexpr int kO = 10;
constexpr int PSTR = 32;   // shorts per h1 pixel (64 B stride)
constexpr int KSPLIT = 8;  // expert GEMM k-split: 9216/8 = 1152

typedef __attribute__((ext_vector_type(8))) short short8;   // 8 bf16
typedef __attribute__((ext_vector_type(4))) float f32x4;    // MFMA acc

__device__ inline unsigned f2bf(float f) {  // fp32 -> bf16 bits, RNE
  unsigned u = __float_as_uint(f);
  return (u + 0x7fffu + ((u >> 16) & 1u)) >> 16;
}
__device__ inline float bf2f(unsigned b) { return __uint_as_float(b << 16); }

// w1 -> MFMA B-frag order, bf16 hi/lo. Layout:
// [e][k>>5][nt][lane][j], lane = ((k>>3)&3)<<4 | (n&15), j = k&7.
// Block 0 additionally packs c2w B-frags and zeroes counts.
__global__ __launch_bounds__(256) void prep_w1(
    const float* __restrict__ w1, ushort* __restrict__ w1ph,
    ushort* __restrict__ w1pl, const float* __restrict__ c2w,
    ushort* __restrict__ Bph, ushort* __restrict__ Bpl,
    int* __restrict__ counts) {
  if (blockIdx.x == 0) {
    if (threadIdx.x < kE) counts[threadIdx.x] = 0;
    for (int i = threadIdx.x; i < 9 * 4 * 64 * 8; i += 256) {
      int j = i & 7, lane = (i >> 3) & 63, nt = (i >> 9) & 3, tap = i >> 11;
      int n = nt * 16 + (lane & 15);
      int c1 = (lane >> 4) * 8 + j;
      float v = c2w[(n * 32 + c1) * 9 + tap];
      unsigned hb = f2bf(v);
      Bph[i] = (ushort)hb;
      Bpl[i] = (ushort)f2bf(v - bf2f(hb));
    }
  }
  int t = blockIdx.x * 256 + threadIdx.x;
  int n = t & 127;
  int rem = t >> 7;
  int k8 = rem % 1152;
  int e = rem / 1152;
  const float* src = w1 + ((size_t)e * kD + (size_t)k8 * 8) * kH + n;
  short8 sh, sl;
#pragma unroll
  for (int j = 0; j < 8; ++j) {
    float v = src[(size_t)j * kH];
    unsigned hb = f2bf(v);
    sh[j] = (short)hb;
    sl[j] = (short)f2bf(v - bf2f(hb));
  }
  size_t base =
      ((((size_t)e * 288 + (k8 >> 2)) * 8 + (n >> 4)) * 64 +
       (((k8 & 3) << 4) | (n & 15))) * 8;
  *(short8*)(w1ph + base) = sh;
  *(short8*)(w1pl + base) = sl;
}

// One 256-thread block per sample. Wave w owns ntile w (16 chans), covers all
// 18 mt tiles: B-frag residency 72 regs/wave (was 144) -> unified VGPR+AGPR
// total ~130-170 -> 3-4 waves/SIMD; LDS caps 3 blocks/CU (R10 post-mortem:
// unified reg file is THE conv occupancy limiter; VGPR_Count hides AGPRs).
// (256,2): min 2 is trivially met; plain bounds let allocator run unbounded
// (R10: 1 block/CU). NUMERICS FROZEN: conv1 loop identical; per output value
// the tap order and Al*Bh -> Ah*Bl -> Ah*Bh chain are identical to R2-R9.
__global__ __launch_bounds__(256, 2) void conv_kernel(
    const float* __restrict__ x, const float* __restrict__ c1w,
    const float* __restrict__ c1b, const float* __restrict__ b2g,
    const ushort* __restrict__ Bph, const ushort* __restrict__ Bpl,
    float* __restrict__ h) {
  __shared__ float xs[784];
  __shared__ float w1s[288];
  __shared__ float b1s[32];
  __shared__ ushort h1h[364 * PSTR];  // 23.3 KB
  __shared__ ushort h1l[364 * PSTR];
  const int b = blockIdx.x, tid = threadIdx.x;
  const int lane = tid & 63, wave = tid >> 6;  // wave = ntile (16 chans)

  short8 Bh[9], Bl[9];
#pragma unroll
  for (int tap = 0; tap < 9; ++tap) {
    int fi = ((tap * 4 + wave) * 64 + lane) * 8;
    Bh[tap] = *(const short8*)(Bph + fi);
    Bl[tap] = *(const short8*)(Bpl + fi);
  }
  float b2v = b2g[wave * 16 + (lane & 15)];

  const float* xb = x + (size_t)b * 784;
  for (int i = tid; i < 784; i += 256) xs[i] = xb[i];
  for (int i = tid; i < 288; i += 256) w1s[i] = c1w[i];
  if (tid < 32) b1s[tid] = c1b[tid];
  __syncthreads();

  float* hb = h + (size_t)b * kD;
  for (int pass = 0; pass < 2; ++pass) {
    for (int i = tid; i < 364 * 16; i += 256) {
      int p = i >> 4, cp = (i & 15) * 2;
      int r = p / 26, col = p - r * 26;
      const float* xr = xs + (pass * 12 + r) * 28 + col;
      const float* w0 = w1s + cp * 9;
      float v0 = b1s[cp], v1 = b1s[cp + 1];
#pragma unroll
      for (int ky = 0; ky < 3; ++ky)
#pragma unroll
        for (int kx = 0; kx < 3; ++kx) {
          float xv = xr[ky * 28 + kx];
          v0 += xv * w0[ky * 3 + kx];
          v1 += xv * w0[9 + ky * 3 + kx];
        }
      v0 = fmaxf(v0, 0.f);
      v1 = fmaxf(v1, 0.f);
      unsigned h0 = f2bf(v0), h1b = f2bf(v1);
      unsigned l0 = f2bf(v0 - bf2f(h0)), l1 = f2bf(v1 - bf2f(h1b));
      *(unsigned*)&h1h[p * PSTR + cp] = h0 | (h1b << 16);
      *(unsigned*)&h1l[p * PSTR + cp] = l0 | (l1 << 16);
    }
    __syncthreads();
    const int m = lane & 15, kg = lane >> 4;
    for (int mt = 0; mt < 18; ++mt) {
      int cell = mt * 4 + (m >> 2), sub = m & 3;
      int cy = cell / 12, cx = cell - cy * 12;
      int yy = 2 * cy + (sub >> 1), xx = 2 * cx + (sub & 1);
      const ushort* ah = h1h + (yy * 26 + xx) * PSTR + kg * 8;
      const ushort* al = h1l + (yy * 26 + xx) * PSTR + kg * 8;
      f32x4 acc = {0.f, 0.f, 0.f, 0.f};
#pragma unroll
      for (int ky = 0; ky < 3; ++ky)
#pragma unroll
        for (int kx = 0; kx < 3; ++kx) {
          const int tap = ky * 3 + kx;
          short8 Ah = *(const short8*)(ah + (ky * 26 + kx) * PSTR);  // b128
          short8 Al = *(const short8*)(al + (ky * 26 + kx) * PSTR);
          acc = __builtin_amdgcn_mfma_f32_16x16x32_bf16(Al, Bh[tap], acc, 0, 0, 0);
          acc = __builtin_amdgcn_mfma_f32_16x16x32_bf16(Ah, Bl[tap], acc, 0, 0, 0);
          acc = __builtin_amdgcn_mfma_f32_16x16x32_bf16(Ah, Bh[tap], acc, 0, 0, 0);
        }
      int cellg = mt * 4 + kg;
      int gy = cellg / 12, gx = cellg - gy * 12;
      int orow = (pass * 6 + gy) * 12 + gx;
      float p0 = fmaxf(fmaxf(acc[0], acc[1]), fmaxf(acc[2], acc[3]));
      hb[(wave * 16 + m) * 144 + orow] = fmaxf(p0 + b2v, 0.f);
    }
    __syncthreads();
  }
}

// 4 tokens per 256-thread block; per-wave numerics frozen (R5 verbatim).
__global__ __launch_bounds__(256) void gate_kernel(
    const float* __restrict__ h, const float* __restrict__ gw,
    int* __restrict__ idx, float* __restrict__ scale,
    int* __restrict__ counts) {
  const int b = blockIdx.x * 4 + (threadIdx.x >> 6);
  const int lane = threadIdx.x & 63;
  const float* hb = h + (size_t)b * kD;
  float acc[kE] = {0, 0, 0, 0, 0, 0, 0, 0};
  for (int i = lane; i < kD; i += 64) {
    float hv = hb[i];
    const float* g = gw + (size_t)i * kE;
#pragma unroll
    for (int e = 0; e < kE; ++e) acc[e] += hv * g[e];
  }
#pragma unroll
  for (int off = 32; off > 0; off >>= 1) {
#pragma unroll
    for (int e = 0; e < kE; ++e) acc[e] += __shfl_down(acc[e], off, 64);
  }
  if (lane == 0) {
    float m = acc[0];
    int bi = 0;
#pragma unroll
    for (int e = 1; e < kE; ++e)
      if (acc[e] > m) { m = acc[e]; bi = e; }
    float s = 0.f;
#pragma unroll
    for (int e = 0; e < kE; ++e) s += expf(acc[e] - m);
    idx[b] = bi;
    scale[b] = 1.0f / s;
    atomicAdd(&counts[bi], 1);
  }
}

// Single block: exclusive scan of counts + bucket scatter via LDS cursors.
__global__ __launch_bounds__(256) void scan_scatter(
    const int* __restrict__ counts, const int* __restrict__ idx,
    int* __restrict__ offsets, int* __restrict__ perm) {
  __shared__ int soff[kE + 1];
  __shared__ int cur[kE];
  if (threadIdx.x == 0) {
    int o = 0;
    for (int e = 0; e < kE; ++e) {
      soff[e] = o;
      cur[e] = o;
      o += counts[e];
    }
    soff[kE] = o;
  }
  __syncthreads();
  for (int b = threadIdx.x; b < kB; b += 256) {
    int e = idx[b];
    int pos = atomicAdd(&cur[e], 1);
    perm[pos] = b;
  }
  if (threadIdx.x <= kE) offsets[threadIdx.x] = soff[threadIdx.x];
}

// MFMA expert GEMM. Grid (e=8, ks=8, tile=16). B staged through LDS once per
// block per bk (R9 win). Numerics frozen vs R4-R10.
__global__ __launch_bounds__(256) void expert_gemm(
    const float* __restrict__ h, const ushort* __restrict__ w1ph,
    const ushort* __restrict__ w1pl, const int* __restrict__ perm,
    const int* __restrict__ offsets, float* __restrict__ preact) {
  const int e = blockIdx.x, ks = blockIdx.y;
  const int start = offsets[e] + blockIdx.z * 64;
  const int end = offsets[e + 1];
  if (start >= end) return;
  const int M = min(64, end - start);
  __shared__ ushort Afh[4096];  // A frags [kstep][g][lane][8], 8 KB
  __shared__ ushort Afl[4096];
  __shared__ ushort Bsh[8192];  // B frags [kstep][nt][lane][8], 16 KB
  __shared__ ushort Bsl[8192];
  __shared__ int rows[64];
  const int tid = threadIdx.x;
  if (tid < 64) rows[tid] = perm[start + min(tid, M - 1)];
  __syncthreads();
  const int wave = tid >> 6, lane = tid & 63;
  const int m15 = lane & 15, kg4 = lane >> 4;
  const int srow = tid >> 2, spart = tid & 3;
  const int kbase = ks * (kD / KSPLIT);
  const float* hp0 = h + (size_t)rows[srow] * kD + kbase + spart * 16;
  const int skstep = spart >> 1, skg = (spart & 1) * 2;
  const int sg = srow >> 4, sm = srow & 15;
  ushort* wh0 = &Afh[((skstep * 4 + sg) * 64 + skg * 16 + sm) * 8];
  ushort* wl0 = &Afl[((skstep * 4 + sg) * 64 + skg * 16 + sm) * 8];
  f32x4 acc[8];
#pragma unroll
  for (int j = 0; j < 8; ++j) acc[j] = {0.f, 0.f, 0.f, 0.f};

  for (int bk = 0; bk < kD / KSPLIT; bk += 64) {
    // ---- stage A ----
#pragma unroll
    for (int c = 0; c < 2; ++c) {
      float4 v0 = *(const float4*)(hp0 + bk + c * 8);
      float4 v1 = *(const float4*)(hp0 + bk + c * 8 + 4);
      short8 ph, pl;
      float f[8] = {v0.x, v0.y, v0.z, v0.w, v1.x, v1.y, v1.z, v1.w};
#pragma unroll
      for (int j = 0; j < 8; ++j) {
        unsigned hb = f2bf(f[j]);
        ph[j] = (short)hb;
        pl[j] = (short)f2bf(f[j] - bf2f(hb));
      }
      *(short8*)(wh0 + c * 128) = ph;
      *(short8*)(wl0 + c * 128) = pl;
    }
    // ---- stage B: 2 kg32 blocks x 4096 shorts, contiguous in w1p ----
    {
      const size_t bbase =
          ((size_t)e * 288 + ((kbase + bk) >> 5)) * 4096;
#pragma unroll
      for (int q = 0; q < 4; ++q) {
        int c = tid + q * 256;  // b128 chunk id, 1024 total
        *(short8*)&Bsh[c * 8] = *(const short8*)(w1ph + bbase + (size_t)c * 8);
        *(short8*)&Bsl[c * 8] = *(const short8*)(w1pl + bbase + (size_t)c * 8);
      }
    }
    __syncthreads();
#pragma unroll
    for (int kstep = 0; kstep < 2; ++kstep) {
      const ushort* af = &Afh[((kstep * 4 + wave) * 64 + lane) * 8];
      short8 ah = *(const short8*)af;
      short8 al = *(const short8*)(af + (Afl - Afh));
      const ushort* bph = &Bsh[kstep * 4096 + lane * 8];
      const ushort* bpl = &Bsl[kstep * 4096 + lane * 8];
#pragma unroll
      for (int nt = 0; nt < 8; ++nt) {
        short8 bh = *(const short8*)(bph + nt * 512);
        short8 bl = *(const short8*)(bpl + nt * 512);
        acc[nt] = __builtin_amdgcn_mfma_f32_16x16x32_bf16(al, bh, acc[nt], 0, 0, 0);
        acc[nt] = __builtin_amdgcn_mfma_f32_16x16x32_bf16(ah, bl, acc[nt], 0, 0, 0);
        acc[nt] = __builtin_amdgcn_mfma_f32_16x16x32_bf16(ah, bh, acc[nt], 0, 0, 0);
      }
    }
    __syncthreads();
  }
  float* pb = preact + (size_t)ks * kB * kH;
#pragma unroll
  for (int r = 0; r < 4; ++r) {
    int row = wave * 16 + kg4 * 4 + r;
    if (row < M) {
      float* pr = pb + (size_t)rows[row] * kH + m15;
#pragma unroll
      for (int nt = 0; nt < 8; ++nt) pr[nt * 16] = acc[nt][r];
    }
  }
}

// Per-token tail: sum k-split slices, bias+relu, w2 matmul, scale, log_softmax.
__global__ __launch_bounds__(64) void expert_tail(
    const float* __restrict__ preact, const float* __restrict__ b1,
    const float* __restrict__ w2, const float* __restrict__ b2,
    const int* __restrict__ idx, const float* __restrict__ scale,
    float* __restrict__ out) {
  const int b = blockIdx.x;
  const int lane = threadIdx.x;
  const int e = idx[b];
  float pa = 0.f, pc = 0.f;
#pragma unroll
  for (int ks = 0; ks < KSPLIT; ++ks) {
    const float* ps = preact + ((size_t)ks * kB + b) * kH;
    pa += ps[lane];
    pc += ps[64 + lane];
  }
  float hea = fmaxf(pa + b1[e * kH + lane], 0.f);
  float heb = fmaxf(pc + b1[e * kH + 64 + lane], 0.f);
  const float* w2a = w2 + ((size_t)e * kH + lane) * kO;
  const float* w2b = w2a + 64 * kO;
  float part[kO];
#pragma unroll
  for (int o = 0; o < kO; ++o) part[o] = hea * w2a[o] + heb * w2b[o];
#pragma unroll
  for (int off = 32; off > 0; off >>= 1)
#pragma unroll
    for (int o = 0; o < kO; ++o) part[o] += __shfl_down(part[o], off, 64);
  if (lane == 0) {
    const float sc = scale[b];
    float v[kO], m = -1e30f;
#pragma unroll
    for (int o = 0; o < kO; ++o) {
      v[o] = (part[o] + b2[e * kO + o]) * sc;
      m = fmaxf(m, v[o]);
    }
    float s = 0.f;
#pragma unroll
    for (int o = 0; o < kO; ++o) s += expf(v[o] - m);
    const float lse = m + logf(s);
#pragma unroll
    for (int o = 0; o < kO; ++o) out[(size_t)b * kO + o] = v[o] - lse;
  }
}

}  // namespace

extern "C" void kernel_launch(void* const* d_in, const int* in_sizes, int n_in,
                              void* d_out, int out_size, void* d_ws,
                              size_t ws_size, hipStream_t stream) {
  (void)in_sizes; (void)n_in; (void)out_size; (void)ws_size;
  const float* x   = (const float*)d_in[0];
  const float* c1w = (const float*)d_in[1];
  const float* c1b = (const float*)d_in[2];
  const float* c2w = (const float*)d_in[3];
  const float* c2b = (const float*)d_in[4];
  const float* gw  = (const float*)d_in[5];
  const float* w1  = (const float*)d_in[6];
  const float* b1  = (const float*)d_in[7];
  const float* w2  = (const float*)d_in[8];
  const float* b2  = (const float*)d_in[9];
  float* out = (float*)d_out;

  char* ws = (char*)d_ws;
  float* h = (float*)ws;
  size_t off = (size_t)kB * kD * sizeof(float);                     // 151.0 MB
  ushort* w1ph = (ushort*)(ws + off); off += (size_t)kE * kD * kH * 2;  // 18.9 MB
  ushort* w1pl = (ushort*)(ws + off); off += (size_t)kE * kD * kH * 2;  // 18.9 MB
  float* preact = (float*)(ws + off); off += (size_t)KSPLIT * kB * kH * 4;  // 16.8 MB
  ushort* Bph = (ushort*)(ws + off);  off += 9 * 4 * 64 * 8 * 2;
  ushort* Bpl = (ushort*)(ws + off);  off += 9 * 4 * 64 * 8 * 2;
  int* idx = (int*)(ws + off);        off += (size_t)kB * 4;
  float* scale = (float*)(ws + off);  off += (size_t)kB * 4;
  int* perm = (int*)(ws + off);       off += (size_t)kB * 4;
  int* counts = (int*)(ws + off);     off += 64;
  int* offsets = (int*)(ws + off);    off += 64;

  prep_w1<<<4608, 256, 0, stream>>>(w1, w1ph, w1pl, c2w, Bph, Bpl, counts);
  conv_kernel<<<kB, 256, 0, stream>>>(x, c1w, c1b, c2b, Bph, Bpl, h);
  gate_kernel<<<kB / 4, 256, 0, stream>>>(h, gw, idx, scale, counts);
  scan_scatter<<<1, 256, 0, stream>>>(counts, idx, offsets, perm);
  dim3 eg(kE, KSPLIT, 16);
  expert_gemm<<<eg, 256, 0, stream>>>(h, w1ph, w1pl, perm, offsets, preact);
  expert_tail<<<kB, 64, 0, stream>>>(preact, b1, w2, b2, idx, scale, out);
}